// Round 2
// baseline (1163.417 us; speedup 1.0000x reference)
//
#include <hip/hip_runtime.h>
#include <stdint.h>

typedef unsigned short u16;
typedef unsigned int u32;
typedef __bf16 bf16x8 __attribute__((ext_vector_type(8)));
typedef float floatx4 __attribute__((ext_vector_type(4)));

static constexpr int NC = 120000;
static constexpr int NF = 240000;

__device__ __forceinline__ float bf2f(u16 u) {
    union { u32 i; float f; } v; v.i = ((u32)u) << 16; return v.f;
}
__device__ __forceinline__ u16 f2bf(float f) {
    union { float f; u32 i; } v; v.f = f;
    u32 r = v.i + 0x7FFFu + ((v.i >> 16) & 1u);
    return (u16)(r >> 16);
}

// xp[i] = bf16(feats_x[i] + feats_skip[i]) for i < NC rows; row NC zeroed (pad row).
// Inputs are FLOAT32 (reference dtype); xp is bf16 for MFMA.
__global__ void add_pad_k(const float* __restrict__ a, const float* __restrict__ b,
                          u16* __restrict__ xp) {
    int idx = blockIdx.x * blockDim.x + threadIdx.x;  // 4 elements per thread
    if (idx >= (NC + 1) * 32) return;
    uint2 vo;
    if (idx < NC * 32) {
        float4 va = ((const float4*)a)[idx];
        float4 vb = ((const float4*)b)[idx];
        vo.x = (u32)f2bf(va.x + vb.x) | ((u32)f2bf(va.y + vb.y) << 16);
        vo.y = (u32)f2bf(va.z + vb.z) | ((u32)f2bf(va.w + vb.w) << 16);
    } else {
        vo.x = vo.y = 0u;
    }
    ((uint2*)xp)[idx] = vo;
}

// Wt[k][co][ci] = bf16(W[k][ci][co]);  W is float32 [K][Cin][64]
__global__ void transpose_w_k(const float* __restrict__ W, u16* __restrict__ Wt,
                              int K, int Cin) {
    int idx = blockIdx.x * blockDim.x + threadIdx.x;
    if (idx >= K * Cin * 64) return;
    int k = idx / (Cin * 64);
    int rem = idx - k * (Cin * 64);
    int ci = rem / 64, co = rem - ci * 64;
    Wt[(k * 64 + co) * Cin + ci] = f2bf(W[idx]);
}

__global__ void fill_k(int* __restrict__ p, int n, int val) {
    int i = blockIdx.x * blockDim.x + threadIdx.x;
    if (i < n) p[i] = val;
}

// inv[k][out] = in  for each valid pair (out indices unique per k).
__global__ void scatter_k(const int* __restrict__ pairs, int* __restrict__ inv,
                          int npairs, int n_out) {
    int i = blockIdx.x * blockDim.x + threadIdx.x;
    if (i >= npairs) return;
    int in = pairs[2 * i], out = pairs[2 * i + 1];
    if (out < n_out) inv[(i / NC) * n_out + out] = in;
}

// Gather-GEMM sparse conv: out[o] = sum_k feats[inv[k][o]] @ W[k].
// 64-row x 64-col output tile per block; bf16 MFMA, fp32 accum.
template <int TCIN, bool LEAKY, bool F32OUT>
__global__ __launch_bounds__(256) void spconv_k(
    const u16* __restrict__ feats, const int* __restrict__ inv,
    const u16* __restrict__ wT, void* __restrict__ outv, int K, int n_out) {
    constexpr int PAD = 8;
    __shared__ __align__(16) u16 A[64][TCIN + PAD];
    const int tid = threadIdx.x;
    const int wave = tid >> 6, lane = tid & 63;
    const int l15 = lane & 15, quad = lane >> 4;
    const int rowbase = blockIdx.x * 64;
    constexpr int TPR = TCIN / 8;        // threads per row (16B chunks)
    constexpr int RPI = 256 / TPR;       // rows gathered per iteration
    const int gr = tid / TPR, gc = tid - (tid / TPR) * TPR;

    floatx4 acc[4];
#pragma unroll
    for (int i = 0; i < 4; ++i) acc[i] = (floatx4)(0.0f);

    for (int k = 0; k < K; ++k) {
        const int* invk = inv + (size_t)k * n_out + rowbase;
        int probe = invk[lane];          // all 4 waves read identical values -> uniform
        if (!__any(probe != NC)) continue;   // skip parity-empty taps (upsample conv)
        __syncthreads();
#pragma unroll
        for (int it = 0; it < 64 / RPI; ++it) {
            int r = it * RPI + gr;
            int src_row = invk[r];
            const uint4* s = (const uint4*)(feats + (size_t)src_row * TCIN) + gc;
            *(uint4*)(&A[r][gc * 8]) = *s;
        }
        __syncthreads();
        const u16* wk = wT + (size_t)k * (64 * TCIN);
#pragma unroll
        for (int kc = 0; kc < TCIN / 32; ++kc) {
            bf16x8 a = *(const bf16x8*)(&A[wave * 16 + l15][kc * 32 + quad * 8]);
#pragma unroll
            for (int nt = 0; nt < 4; ++nt) {
                bf16x8 b = *(const bf16x8*)(wk + (nt * 16 + l15) * TCIN + kc * 32 + quad * 8);
                acc[nt] = __builtin_amdgcn_mfma_f32_16x16x32_bf16(a, b, acc[nt], 0, 0, 0);
            }
        }
    }
    // C/D layout: col = lane&15, row = quad*4 + reg   [m89-verified]
#pragma unroll
    for (int nt = 0; nt < 4; ++nt) {
#pragma unroll
        for (int r = 0; r < 4; ++r) {
            float v = acc[nt][r];
            if (LEAKY) v = v > 0.f ? v : 0.01f * v;
            int row = rowbase + wave * 16 + quad * 4 + r;
            size_t oi = (size_t)row * 64 + nt * 16 + l15;
            if (F32OUT) ((float*)outv)[oi] = v;
            else        ((u16*)outv)[oi] = f2bf(v);
        }
    }
}

// Per-channel sum/sumsq over [NC][64] bf16, fp32 accumulation.
__global__ void stats_k(const u16* __restrict__ raw, float* __restrict__ sums) {
    int tid = threadIdx.x;
    int wave = tid >> 6, c = tid & 63;
    int gw = blockIdx.x * 4 + wave;
    int GW = gridDim.x * 4;
    float s = 0.f, q = 0.f;
    for (int r = gw; r < NC; r += GW) {
        float v = bf2f(raw[(size_t)r * 64 + c]);
        s += v; q += v * v;
    }
    __shared__ float sb[4][64], qb[4][64];
    sb[wave][c] = s; qb[wave][c] = q;
    __syncthreads();
    if (tid < 64) {
        float S = sb[0][tid] + sb[1][tid] + sb[2][tid] + sb[3][tid];
        float Q = qb[0][tid] + qb[1][tid] + qb[2][tid] + qb[3][tid];
        atomicAdd(&sums[tid], S);
        atomicAdd(&sums[64 + tid], Q);
    }
}

// scale = g*rsqrt(var+eps); shift = b - mean*scale  (biased var, matches jnp.var)
__global__ void finalize_k(const float* __restrict__ sums, const float* __restrict__ g,
                           const float* __restrict__ bb, float* __restrict__ scsh) {
    int c = threadIdx.x;
    if (c < 64) {
        float m = sums[c] / (float)NC;
        float v = sums[64 + c] / (float)NC - m * m;
        float sc = g[c] * rsqrtf(v + 1e-5f);
        scsh[c] = sc;
        scsh[64 + c] = bb[c] - m * sc;
    }
}

__global__ void apply0_k(const u16* __restrict__ raw, const float* __restrict__ scsh,
                         u16* __restrict__ up) {
    int idx = blockIdx.x * blockDim.x + threadIdx.x;
    if (idx >= (NC + 1) * 64) return;
    int c = idx & 63, i = idx >> 6;
    up[idx] = (i < NC) ? f2bf(bf2f(raw[idx]) * scsh[c] + scsh[64 + c]) : (u16)0;
}

__global__ void apply12_k(const u16* __restrict__ rb, const u16* __restrict__ rc,
                          const float* __restrict__ s1, const float* __restrict__ s2,
                          u16* __restrict__ up) {
    int idx = blockIdx.x * blockDim.x + threadIdx.x;
    if (idx >= (NC + 1) * 64) return;
    int c = idx & 63, i = idx >> 6;
    float v = bf2f(rb[idx]) * s1[c] + s1[64 + c] + bf2f(rc[idx]) * s2[c] + s2[64 + c];
    up[idx] = (i < NC) ? f2bf(v) : (u16)0;
}

extern "C" void kernel_launch(void* const* d_in, const int* in_sizes, int n_in,
                              void* d_out, int out_size, void* d_ws, size_t ws_size,
                              hipStream_t stream) {
    const float* feats_x    = (const float*)d_in[0];
    const float* feats_skip = (const float*)d_in[1];
    const float* W_trans    = (const float*)d_in[2];
    const float* W1         = (const float*)d_in[3];
    const float* W2         = (const float*)d_in[4];
    const float* W_up       = (const float*)d_in[5];
    const float* g0 = (const float*)d_in[6],  *b0 = (const float*)d_in[7];
    const float* g1 = (const float*)d_in[8],  *b1 = (const float*)d_in[9];
    const float* g2 = (const float*)d_in[10], *b2 = (const float*)d_in[11];
    const int* pairs33 = (const int*)d_in[12];
    const int* pairs13 = (const int*)d_in[13];
    const int* pairs31 = (const int*)d_in[14];
    const int* pairs_up = (const int*)d_in[15];
    float* outp = (float*)d_out;   // reference output dtype: float32

    char* ws = (char*)d_ws;
    size_t off = 0;
    auto alloc = [&](size_t bytes) {
        char* p = ws + off;
        off += (bytes + 255) & ~(size_t)255;
        return p;
    };
    u16* xp    = (u16*)alloc(30720256);   // [NC+1][128] bf16; later overlaid by inv_up
    int* inv33 = (int*)alloc(12960000);   // [27][NC]; (+inv13) later overlaid by upE
    int* inv13 = (int*)alloc(4320000);    // [9][NC]
    int* inv31 = (int*)alloc(4320000);    // [9][NC]
    u16* rawA  = (u16*)alloc(15360000);   // [NC][64] bf16; later rawB
    u16* rawC  = (u16*)alloc(15360000);   // [NC][64]
    u16* upA   = (u16*)alloc(15360128);   // [NC+1][64]
    u16* WtA   = (u16*)alloc(27 * 128 * 64 * 2);
    u16* Wt1   = (u16*)alloc(9 * 64 * 64 * 2);
    u16* Wt2   = (u16*)alloc(9 * 64 * 64 * 2);
    u16* WtU   = (u16*)alloc(27 * 64 * 64 * 2);
    float* stats = (float*)alloc(6 * 128 * 4);
    int* inv_up = (int*)xp;               // [27][NF] = 25.92MB — xp (30.7MB) dead after convA
    u16* rawB = rawA;                     // rawA dead after apply0
    u16* upE  = (u16*)inv33;              // needs 15.36MB; inv33+inv13 = 17.28MB, dead after convB/C
    float *sums0 = stats,        *sums1 = stats + 128, *sums2 = stats + 256;
    float *scsh0 = stats + 384,  *scsh1 = stats + 512, *scsh2 = stats + 640;

    const int B = 256;
    hipMemsetAsync(stats, 0, 6 * 128 * 4, stream);

    transpose_w_k<<<(27 * 128 * 64 + 255) / 256, B, 0, stream>>>(W_trans, WtA, 27, 128);
    transpose_w_k<<<(9 * 64 * 64 + 255) / 256, B, 0, stream>>>(W1, Wt1, 9, 64);
    transpose_w_k<<<(9 * 64 * 64 + 255) / 256, B, 0, stream>>>(W2, Wt2, 9, 64);
    transpose_w_k<<<(27 * 64 * 64 + 255) / 256, B, 0, stream>>>(W_up, WtU, 27, 64);

    add_pad_k<<<((NC + 1) * 32 + 255) / 256, B, 0, stream>>>(feats_x, feats_skip, xp);

    fill_k<<<(27 * NC + 255) / 256, B, 0, stream>>>(inv33, 27 * NC, NC);
    fill_k<<<(9 * NC + 255) / 256, B, 0, stream>>>(inv13, 9 * NC, NC);
    fill_k<<<(9 * NC + 255) / 256, B, 0, stream>>>(inv31, 9 * NC, NC);
    scatter_k<<<(27 * NC + 255) / 256, B, 0, stream>>>(pairs33, inv33, 27 * NC, NC);
    scatter_k<<<(9 * NC + 255) / 256, B, 0, stream>>>(pairs13, inv13, 9 * NC, NC);
    scatter_k<<<(9 * NC + 255) / 256, B, 0, stream>>>(pairs31, inv31, 9 * NC, NC);

    // conv_trans (27 taps, Cin=128) + leakyReLU fused
    spconv_k<128, true, false><<<NC / 64, B, 0, stream>>>(xp, inv33, WtA, rawA, 27, NC);
    stats_k<<<120, B, 0, stream>>>(rawA, sums0);
    finalize_k<<<1, 64, 0, stream>>>(sums0, g0, b0, scsh0);
    apply0_k<<<((NC + 1) * 64 + 255) / 256, B, 0, stream>>>(rawA, scsh0, upA);

    // xp dead — build upsample inverse map in its region
    fill_k<<<(27 * NF + 255) / 256, B, 0, stream>>>(inv_up, 27 * NF, NC);
    scatter_k<<<(27 * NC + 255) / 256, B, 0, stream>>>(pairs_up, inv_up, 27 * NC, NF);

    // conv1x3 / conv3x1 (9 taps each, Cin=64)
    spconv_k<64, false, false><<<NC / 64, B, 0, stream>>>(upA, inv13, Wt1, rawB, 9, NC);
    stats_k<<<120, B, 0, stream>>>(rawB, sums1);
    finalize_k<<<1, 64, 0, stream>>>(sums1, g1, b1, scsh1);

    spconv_k<64, false, false><<<NC / 64, B, 0, stream>>>(upA, inv31, Wt2, rawC, 9, NC);
    stats_k<<<120, B, 0, stream>>>(rawC, sums2);
    finalize_k<<<1, 64, 0, stream>>>(sums2, g2, b2, scsh2);

    apply12_k<<<((NC + 1) * 64 + 255) / 256, B, 0, stream>>>(rawB, rawC, scsh1, scsh2, upE);

    // upsample inverse conv (27 taps, Cin=64) -> d_out (float32)
    spconv_k<64, false, true><<<NF / 64, B, 0, stream>>>(upE, inv_up, WtU, outp, 27, NF);
}

// Round 3
// 796.238 us; speedup vs baseline: 1.4611x; 1.4611x over previous
//
#include <hip/hip_runtime.h>
#include <stdint.h>

typedef unsigned short u16;
typedef unsigned int u32;
typedef __bf16 bf16x8 __attribute__((ext_vector_type(8)));
typedef float floatx4 __attribute__((ext_vector_type(4)));

static constexpr int NC = 120000;
static constexpr int NF = 240000;

__device__ __forceinline__ float bf2f(u16 u) {
    union { u32 i; float f; } v; v.i = ((u32)u) << 16; return v.f;
}
__device__ __forceinline__ u16 f2bf(float f) {
    union { float f; u32 i; } v; v.f = f;
    u32 r = v.i + 0x7FFFu + ((v.i >> 16) & 1u);
    return (u16)(r >> 16);
}

// xp[i] = bf16(feats_x[i] + feats_skip[i]) for i < NC rows; row NC zeroed (pad row).
__global__ void add_pad_k(const float* __restrict__ a, const float* __restrict__ b,
                          u16* __restrict__ xp) {
    int idx = blockIdx.x * blockDim.x + threadIdx.x;  // 4 elements per thread
    if (idx >= (NC + 1) * 32) return;
    uint2 vo;
    if (idx < NC * 32) {
        float4 va = ((const float4*)a)[idx];
        float4 vb = ((const float4*)b)[idx];
        vo.x = (u32)f2bf(va.x + vb.x) | ((u32)f2bf(va.y + vb.y) << 16);
        vo.y = (u32)f2bf(va.z + vb.z) | ((u32)f2bf(va.w + vb.w) << 16);
    } else {
        vo.x = vo.y = 0u;
    }
    ((uint2*)xp)[idx] = vo;
}

// Wt[k][co][ci] = bf16(W[k][ci][co]);  W is float32 [K][Cin][64]
__global__ void transpose_w_k(const float* __restrict__ W, u16* __restrict__ Wt,
                              int K, int Cin) {
    int idx = blockIdx.x * blockDim.x + threadIdx.x;
    if (idx >= K * Cin * 64) return;
    int k = idx / (Cin * 64);
    int rem = idx - k * (Cin * 64);
    int ci = rem / 64, co = rem - ci * 64;
    Wt[(k * 64 + co) * Cin + ci] = f2bf(W[idx]);
}

__global__ void fill_k(int* __restrict__ p, int n, int val) {
    int i = blockIdx.x * blockDim.x + threadIdx.x;
    if (i < n) p[i] = val;
}

// inv[k][out] = in  for each valid pair (out indices unique per k).
__global__ void scatter_k(const int* __restrict__ pairs, int* __restrict__ inv,
                          int npairs, int n_out) {
    int i = blockIdx.x * blockDim.x + threadIdx.x;
    if (i >= npairs) return;
    int in = pairs[2 * i], out = pairs[2 * i + 1];
    if (out < n_out) inv[(i / NC) * n_out + out] = in;
}

// Barrier-free gather-GEMM sparse conv.
// Block = 4 waves; each wave owns 16 rows x 64 cols of R row-tiles (R*64 rows/block).
// k outer: B(k) loaded to VGPRs once, reused across R tile streams (ILP).
// A-fragments gathered global->VGPR directly (no LDS, no __syncthreads).
template <int TCIN, int R, bool LEAKY, bool F32OUT, bool SKIP>
__global__ __launch_bounds__(256, 2) void spconv_k(
    const u16* __restrict__ feats, const int* __restrict__ inv,
    const u16* __restrict__ wT, void* __restrict__ outv, int K, int n_out) {
    constexpr int KC = TCIN / 32;
    const int tid = threadIdx.x;
    const int wave = tid >> 6, lane = tid & 63;
    const int l15 = lane & 15, quad = lane >> 4;
    const int blockrow = blockIdx.x * (R * 64);
    const int base = blockrow + wave * 16 + l15;  // per-lane index position, tile 0

    floatx4 acc[R][4];
#pragma unroll
    for (int t = 0; t < R; ++t)
#pragma unroll
        for (int nt = 0; nt < 4; ++nt) acc[t][nt] = (floatx4)(0.0f);

    int rows[R];
#pragma unroll
    for (int t = 0; t < R; ++t) rows[t] = inv[base + t * 64];

    for (int k = 0; k < K; ++k) {
        // prefetch next tap's indices while this tap computes
        int rows_n[R];
        if (k + 1 < K) {
            const int* invn = inv + (size_t)(k + 1) * n_out;
#pragma unroll
            for (int t = 0; t < R; ++t) rows_n[t] = invn[base + t * 64];
        }
        bool any = !SKIP;
        if (SKIP) {
#pragma unroll
            for (int t = 0; t < R; ++t) any = any || __any(rows[t] != NC);
        }
        if (any) {
            // B(k) into registers once; reused by all R tiles (80/40 MFMAs per load set)
            const u16* wk = wT + (size_t)k * (64 * TCIN);
            bf16x8 b[KC][4];
#pragma unroll
            for (int kc = 0; kc < KC; ++kc)
#pragma unroll
                for (int nt = 0; nt < 4; ++nt)
                    b[kc][nt] = *(const bf16x8*)(wk + (nt * 16 + l15) * TCIN + kc * 32 + quad * 8);
#pragma unroll
            for (int t = 0; t < R; ++t) {
                const u16* ap = feats + (size_t)rows[t] * TCIN + quad * 8;
                bf16x8 a[KC];
#pragma unroll
                for (int kc = 0; kc < KC; ++kc) a[kc] = *(const bf16x8*)(ap + kc * 32);
#pragma unroll
                for (int kc = 0; kc < KC; ++kc)
#pragma unroll
                    for (int nt = 0; nt < 4; ++nt)
                        acc[t][nt] = __builtin_amdgcn_mfma_f32_16x16x32_bf16(a[kc], b[kc][nt], acc[t][nt], 0, 0, 0);
            }
        }
#pragma unroll
        for (int t = 0; t < R; ++t) rows[t] = rows_n[t];
    }
    // C/D layout: col = lane&15, row = quad*4 + reg   [verified by round-2 pass]
#pragma unroll
    for (int t = 0; t < R; ++t) {
#pragma unroll
        for (int nt = 0; nt < 4; ++nt) {
#pragma unroll
            for (int r = 0; r < 4; ++r) {
                float v = acc[t][nt][r];
                if (LEAKY) v = v > 0.f ? v : 0.01f * v;
                int row = blockrow + t * 64 + wave * 16 + quad * 4 + r;
                size_t oi = (size_t)row * 64 + nt * 16 + l15;
                if (F32OUT) ((float*)outv)[oi] = v;
                else        ((u16*)outv)[oi] = f2bf(v);
            }
        }
    }
}

// Per-channel sum/sumsq over [NC][64] bf16, fp32 accumulation.
__global__ void stats_k(const u16* __restrict__ raw, float* __restrict__ sums) {
    int tid = threadIdx.x;
    int wave = tid >> 6, c = tid & 63;
    int gw = blockIdx.x * 4 + wave;
    int GW = gridDim.x * 4;
    float s = 0.f, q = 0.f;
    for (int r = gw; r < NC; r += GW) {
        float v = bf2f(raw[(size_t)r * 64 + c]);
        s += v; q += v * v;
    }
    __shared__ float sb[4][64], qb[4][64];
    sb[wave][c] = s; qb[wave][c] = q;
    __syncthreads();
    if (tid < 64) {
        float S = sb[0][tid] + sb[1][tid] + sb[2][tid] + sb[3][tid];
        float Q = qb[0][tid] + qb[1][tid] + qb[2][tid] + qb[3][tid];
        atomicAdd(&sums[tid], S);
        atomicAdd(&sums[64 + tid], Q);
    }
}

// scale = g*rsqrt(var+eps); shift = b - mean*scale  (biased var, matches jnp.var)
__global__ void finalize_k(const float* __restrict__ sums, const float* __restrict__ g,
                           const float* __restrict__ bb, float* __restrict__ scsh) {
    int c = threadIdx.x;
    if (c < 64) {
        float m = sums[c] / (float)NC;
        float v = sums[64 + c] / (float)NC - m * m;
        float sc = g[c] * rsqrtf(v + 1e-5f);
        scsh[c] = sc;
        scsh[64 + c] = bb[c] - m * sc;
    }
}

__global__ void apply0_k(const u16* __restrict__ raw, const float* __restrict__ scsh,
                         u16* __restrict__ up) {
    int idx = blockIdx.x * blockDim.x + threadIdx.x;
    if (idx >= (NC + 1) * 64) return;
    int c = idx & 63, i = idx >> 6;
    up[idx] = (i < NC) ? f2bf(bf2f(raw[idx]) * scsh[c] + scsh[64 + c]) : (u16)0;
}

__global__ void apply12_k(const u16* __restrict__ rb, const u16* __restrict__ rc,
                          const float* __restrict__ s1, const float* __restrict__ s2,
                          u16* __restrict__ up) {
    int idx = blockIdx.x * blockDim.x + threadIdx.x;
    if (idx >= (NC + 1) * 64) return;
    int c = idx & 63, i = idx >> 6;
    float v = bf2f(rb[idx]) * s1[c] + s1[64 + c] + bf2f(rc[idx]) * s2[c] + s2[64 + c];
    up[idx] = (i < NC) ? f2bf(v) : (u16)0;
}

extern "C" void kernel_launch(void* const* d_in, const int* in_sizes, int n_in,
                              void* d_out, int out_size, void* d_ws, size_t ws_size,
                              hipStream_t stream) {
    const float* feats_x    = (const float*)d_in[0];
    const float* feats_skip = (const float*)d_in[1];
    const float* W_trans    = (const float*)d_in[2];
    const float* W1         = (const float*)d_in[3];
    const float* W2         = (const float*)d_in[4];
    const float* W_up       = (const float*)d_in[5];
    const float* g0 = (const float*)d_in[6],  *b0 = (const float*)d_in[7];
    const float* g1 = (const float*)d_in[8],  *b1 = (const float*)d_in[9];
    const float* g2 = (const float*)d_in[10], *b2 = (const float*)d_in[11];
    const int* pairs33 = (const int*)d_in[12];
    const int* pairs13 = (const int*)d_in[13];
    const int* pairs31 = (const int*)d_in[14];
    const int* pairs_up = (const int*)d_in[15];
    float* outp = (float*)d_out;   // reference output dtype: float32

    char* ws = (char*)d_ws;
    size_t off = 0;
    auto alloc = [&](size_t bytes) {
        char* p = ws + off;
        off += (bytes + 255) & ~(size_t)255;
        return p;
    };
    u16* xp    = (u16*)alloc(30720256);   // [NC+1][128] bf16; later overlaid by inv_up
    int* inv33 = (int*)alloc(12960000);   // [27][NC]; (+inv13) later overlaid by upE
    int* inv13 = (int*)alloc(4320000);    // [9][NC]
    int* inv31 = (int*)alloc(4320000);    // [9][NC]
    u16* rawA  = (u16*)alloc(15360000);   // [NC][64] bf16; later rawB
    u16* rawC  = (u16*)alloc(15360000);   // [NC][64]
    u16* upA   = (u16*)alloc(15360128);   // [NC+1][64]
    u16* WtA   = (u16*)alloc(27 * 128 * 64 * 2);
    u16* Wt1   = (u16*)alloc(9 * 64 * 64 * 2);
    u16* Wt2   = (u16*)alloc(9 * 64 * 64 * 2);
    u16* WtU   = (u16*)alloc(27 * 64 * 64 * 2);
    float* stats = (float*)alloc(6 * 128 * 4);
    int* inv_up = (int*)xp;               // [27][NF] = 25.92MB — xp (30.7MB) dead after convA
    u16* rawB = rawA;                     // rawA dead after apply0
    u16* upE  = (u16*)inv33;              // inv33+inv13 dead after convB/C
    float *sums0 = stats,        *sums1 = stats + 128, *sums2 = stats + 256;
    float *scsh0 = stats + 384,  *scsh1 = stats + 512, *scsh2 = stats + 640;

    const int B = 256;
    hipMemsetAsync(stats, 0, 6 * 128 * 4, stream);

    transpose_w_k<<<(27 * 128 * 64 + 255) / 256, B, 0, stream>>>(W_trans, WtA, 27, 128);
    transpose_w_k<<<(9 * 64 * 64 + 255) / 256, B, 0, stream>>>(W1, Wt1, 9, 64);
    transpose_w_k<<<(9 * 64 * 64 + 255) / 256, B, 0, stream>>>(W2, Wt2, 9, 64);
    transpose_w_k<<<(27 * 64 * 64 + 255) / 256, B, 0, stream>>>(W_up, WtU, 27, 64);

    add_pad_k<<<((NC + 1) * 32 + 255) / 256, B, 0, stream>>>(feats_x, feats_skip, xp);

    fill_k<<<(27 * NC + 255) / 256, B, 0, stream>>>(inv33, 27 * NC, NC);
    fill_k<<<(9 * NC + 255) / 256, B, 0, stream>>>(inv13, 9 * NC, NC);
    fill_k<<<(9 * NC + 255) / 256, B, 0, stream>>>(inv31, 9 * NC, NC);
    scatter_k<<<(27 * NC + 255) / 256, B, 0, stream>>>(pairs33, inv33, 27 * NC, NC);
    scatter_k<<<(9 * NC + 255) / 256, B, 0, stream>>>(pairs13, inv13, 9 * NC, NC);
    scatter_k<<<(9 * NC + 255) / 256, B, 0, stream>>>(pairs31, inv31, 9 * NC, NC);

    // conv_trans (27 taps, Cin=128) + leakyReLU fused. 375 blocks x 320 rows = 120000.
    spconv_k<128, 5, true, false, false><<<375, B, 0, stream>>>(xp, inv33, WtA, rawA, 27, NC);
    stats_k<<<120, B, 0, stream>>>(rawA, sums0);
    finalize_k<<<1, 64, 0, stream>>>(sums0, g0, b0, scsh0);
    apply0_k<<<((NC + 1) * 64 + 255) / 256, B, 0, stream>>>(rawA, scsh0, upA);

    // xp dead — build upsample inverse map in its region
    fill_k<<<(27 * NF + 255) / 256, B, 0, stream>>>(inv_up, 27 * NF, NC);
    scatter_k<<<(27 * NC + 255) / 256, B, 0, stream>>>(pairs_up, inv_up, 27 * NC, NF);

    // conv1x3 / conv3x1 (9 taps each, Cin=64)
    spconv_k<64, 5, false, false, false><<<375, B, 0, stream>>>(upA, inv13, Wt1, rawB, 9, NC);
    stats_k<<<120, B, 0, stream>>>(rawB, sums1);
    finalize_k<<<1, 64, 0, stream>>>(sums1, g1, b1, scsh1);

    spconv_k<64, 5, false, false, false><<<375, B, 0, stream>>>(upA, inv31, Wt2, rawC, 9, NC);
    stats_k<<<120, B, 0, stream>>>(rawC, sums2);
    finalize_k<<<1, 64, 0, stream>>>(sums2, g2, b2, scsh2);

    apply12_k<<<((NC + 1) * 64 + 255) / 256, B, 0, stream>>>(rawB, rawC, scsh1, scsh2, upE);

    // upsample inverse conv (27 taps, Cin=64, parity skip) -> d_out (float32)
    // 750 blocks x 320 rows = 240000.
    spconv_k<64, 5, false, true, true><<<750, B, 0, stream>>>(upE, inv_up, WtU, outp, 27, NF);
}

// Round 4
// 751.624 us; speedup vs baseline: 1.5479x; 1.0594x over previous
//
#include <hip/hip_runtime.h>
#include <stdint.h>

typedef unsigned short u16;
typedef unsigned int u32;
typedef __bf16 bf16x8 __attribute__((ext_vector_type(8)));
typedef float floatx4 __attribute__((ext_vector_type(4)));

static constexpr int NC = 120000;
static constexpr int NF = 240000;

__device__ __forceinline__ float bf2f(u16 u) {
    union { u32 i; float f; } v; v.i = ((u32)u) << 16; return v.f;
}
__device__ __forceinline__ u16 f2bf(float f) {
    union { float f; u32 i; } v; v.f = f;
    u32 r = v.i + 0x7FFFu + ((v.i >> 16) & 1u);
    return (u16)(r >> 16);
}

// xp[i] = bf16(feats_x[i] + feats_skip[i]) for i < NC rows; row NC zeroed (pad row).
__global__ void add_pad_k(const float* __restrict__ a, const float* __restrict__ b,
                          u16* __restrict__ xp) {
    int idx = blockIdx.x * blockDim.x + threadIdx.x;  // 4 elements per thread
    if (idx >= (NC + 1) * 32) return;
    uint2 vo;
    if (idx < NC * 32) {
        float4 va = ((const float4*)a)[idx];
        float4 vb = ((const float4*)b)[idx];
        vo.x = (u32)f2bf(va.x + vb.x) | ((u32)f2bf(va.y + vb.y) << 16);
        vo.y = (u32)f2bf(va.z + vb.z) | ((u32)f2bf(va.w + vb.w) << 16);
    } else {
        vo.x = vo.y = 0u;
    }
    ((uint2*)xp)[idx] = vo;
}

// Wt[k][co][ci] = bf16(W[k][ci][co]);  W is float32 [K][Cin][64]
__global__ void transpose_w_k(const float* __restrict__ W, u16* __restrict__ Wt,
                              int K, int Cin) {
    int idx = blockIdx.x * blockDim.x + threadIdx.x;
    if (idx >= K * Cin * 64) return;
    int k = idx / (Cin * 64);
    int rem = idx - k * (Cin * 64);
    int ci = rem / 64, co = rem - ci * 64;
    Wt[(k * 64 + co) * Cin + ci] = f2bf(W[idx]);
}

__global__ void fill_k(int* __restrict__ p, int n, int val) {
    int i = blockIdx.x * blockDim.x + threadIdx.x;
    if (i < n) p[i] = val;
}

// inv[k][out] = in  for each valid pair (out indices unique per k).
__global__ void scatter_k(const int* __restrict__ pairs, int* __restrict__ inv,
                          int npairs, int n_out) {
    int i = blockIdx.x * blockDim.x + threadIdx.x;
    if (i >= npairs) return;
    int in = pairs[2 * i], out = pairs[2 * i + 1];
    if (out < n_out) inv[(i / NC) * n_out + out] = in;
}

// Barrier-free, register-pipelined gather-GEMM sparse conv.
// Dual problem sets selected by blockIdx (grid concat) to fuse independent convs.
// Per wave: R row-tiles of 16 rows x 64 cols. k fully unrolled; A-fragments
// double-buffered in registers (prefetch tap k+1 during tap k's MFMAs); row
// indices prefetched two taps ahead. Per-tile liveness skip (dummy row == NC).
template <int TCIN, int K, int R, bool LEAKY, bool F32OUT, int MINW>
__global__ __launch_bounds__(256, MINW) void spconv_k(
    const u16* __restrict__ feats,
    const int* __restrict__ invA, const u16* __restrict__ wTA, void* __restrict__ outA,
    const int* __restrict__ invB, const u16* __restrict__ wTB, void* __restrict__ outB,
    int nb0, int n_outA, int n_outB) {
    constexpr int KC = TCIN / 32;
    const int tid = threadIdx.x;
    const int wave = tid >> 6, lane = tid & 63;
    const int l15 = lane & 15, quad = lane >> 4;
    const bool second = (int)blockIdx.x >= nb0;
    const int bid = second ? (int)blockIdx.x - nb0 : (int)blockIdx.x;
    const int* __restrict__ inv = second ? invB : invA;
    const u16* __restrict__ wT  = second ? wTB : wTA;
    void* __restrict__ outv     = second ? outB : outA;
    const int n_out             = second ? n_outB : n_outA;

    const int blockrow = bid * (R * 64);
    const int base = blockrow + wave * 16 + l15;

    floatx4 acc[R][4];
#pragma unroll
    for (int t = 0; t < R; ++t)
#pragma unroll
        for (int nt = 0; nt < 4; ++nt) acc[t][nt] = (floatx4)(0.0f);

    int rc[R], rn[R];
#pragma unroll
    for (int t = 0; t < R; ++t) rc[t] = inv[base + t * 64];
#pragma unroll
    for (int t = 0; t < R; ++t) rn[t] = inv[n_out + base + t * 64];

    bf16x8 abuf[2][R][KC];
    // prologue: gather A for tap 0 (live tiles only)
#pragma unroll
    for (int t = 0; t < R; ++t) {
        if (__any(rc[t] != NC)) {
            const u16* ap = feats + (size_t)rc[t] * TCIN + quad * 8;
#pragma unroll
            for (int kc = 0; kc < KC; ++kc) abuf[0][t][kc] = *(const bf16x8*)(ap + kc * 32);
        }
    }

#pragma unroll
    for (int k = 0; k < K; ++k) {
        const int cur = k & 1, nxt = cur ^ 1;
        int rf[R];
#pragma unroll
        for (int t = 0; t < R; ++t) rf[t] = NC;
        if (k + 2 < K) {
            const int* invf = inv + (size_t)(k + 2) * n_out;
#pragma unroll
            for (int t = 0; t < R; ++t) rf[t] = invf[base + t * 64];
        }
        bool lv[R], any = false;
#pragma unroll
        for (int t = 0; t < R; ++t) { lv[t] = __any(rc[t] != NC); any = any || lv[t]; }
        bf16x8 b[KC][4];
        if (any) {
            const u16* wk = wT + (size_t)k * (64 * TCIN);
#pragma unroll
            for (int kc = 0; kc < KC; ++kc)
#pragma unroll
                for (int nt = 0; nt < 4; ++nt)
                    b[kc][nt] = *(const bf16x8*)(wk + (nt * 16 + l15) * TCIN + kc * 32 + quad * 8);
        }
        // prefetch A for tap k+1 into the other buffer (before MFMAs issue)
        if (k + 1 < K) {
#pragma unroll
            for (int t = 0; t < R; ++t) {
                if (__any(rn[t] != NC)) {
                    const u16* ap = feats + (size_t)rn[t] * TCIN + quad * 8;
#pragma unroll
                    for (int kc = 0; kc < KC; ++kc) abuf[nxt][t][kc] = *(const bf16x8*)(ap + kc * 32);
                }
            }
        }
#pragma unroll
        for (int t = 0; t < R; ++t) {
            if (lv[t]) {
#pragma unroll
                for (int kc = 0; kc < KC; ++kc)
#pragma unroll
                    for (int nt = 0; nt < 4; ++nt)
                        acc[t][nt] = __builtin_amdgcn_mfma_f32_16x16x32_bf16(
                            abuf[cur][t][kc], b[kc][nt], acc[t][nt], 0, 0, 0);
            }
        }
#pragma unroll
        for (int t = 0; t < R; ++t) { rc[t] = rn[t]; rn[t] = rf[t]; }
    }
    // C/D layout: col = lane&15, row = quad*4 + reg
#pragma unroll
    for (int t = 0; t < R; ++t) {
#pragma unroll
        for (int nt = 0; nt < 4; ++nt) {
#pragma unroll
            for (int r = 0; r < 4; ++r) {
                float v = acc[t][nt][r];
                if (LEAKY) v = v > 0.f ? v : 0.01f * v;
                int row = blockrow + t * 64 + wave * 16 + quad * 4 + r;
                size_t oi = (size_t)row * 64 + nt * 16 + l15;
                if (F32OUT) ((float*)outv)[oi] = v;
                else        ((u16*)outv)[oi] = f2bf(v);
            }
        }
    }
}

// Per-channel sum/sumsq over two [NC][64] bf16 buffers (grid halves), fp32 accum.
__global__ void stats2_k(const u16* __restrict__ ra, const u16* __restrict__ rb,
                         float* __restrict__ sa, float* __restrict__ sb, int half) {
    const u16* raw = ((int)blockIdx.x < half) ? ra : rb;
    float* sums    = ((int)blockIdx.x < half) ? sa : sb;
    int bx = ((int)blockIdx.x < half) ? (int)blockIdx.x : (int)blockIdx.x - half;
    int tid = threadIdx.x;
    int wave = tid >> 6, c = tid & 63;
    int gw = bx * 4 + wave;
    int GW = half * 4;
    float s = 0.f, q = 0.f;
    for (int r = gw; r < NC; r += GW) {
        float v = bf2f(raw[(size_t)r * 64 + c]);
        s += v; q += v * v;
    }
    __shared__ float sbm[4][64], qbm[4][64];
    sbm[wave][c] = s; qbm[wave][c] = q;
    __syncthreads();
    if (tid < 64) {
        float S = sbm[0][tid] + sbm[1][tid] + sbm[2][tid] + sbm[3][tid];
        float Q = qbm[0][tid] + qbm[1][tid] + qbm[2][tid] + qbm[3][tid];
        atomicAdd(&sums[tid], S);
        atomicAdd(&sums[64 + tid], Q);
    }
}

// scale = g*rsqrt(var+eps); shift = b - mean*scale  (biased var, matches jnp.var)
__global__ void finalize_k(const float* __restrict__ sums, const float* __restrict__ g,
                           const float* __restrict__ bb, float* __restrict__ scsh) {
    int c = threadIdx.x;
    if (c < 64) {
        float m = sums[c] / (float)NC;
        float v = sums[64 + c] / (float)NC - m * m;
        float sc = g[c] * rsqrtf(v + 1e-5f);
        scsh[c] = sc;
        scsh[64 + c] = bb[c] - m * sc;
    }
}

__global__ void apply0_k(const u16* __restrict__ raw, const float* __restrict__ scsh,
                         u16* __restrict__ up) {
    int idx = blockIdx.x * blockDim.x + threadIdx.x;
    if (idx >= (NC + 1) * 64) return;
    int c = idx & 63, i = idx >> 6;
    up[idx] = (i < NC) ? f2bf(bf2f(raw[idx]) * scsh[c] + scsh[64 + c]) : (u16)0;
}

__global__ void apply12_k(const u16* __restrict__ rb, const u16* __restrict__ rc,
                          const float* __restrict__ s1, const float* __restrict__ s2,
                          u16* __restrict__ up) {
    int idx = blockIdx.x * blockDim.x + threadIdx.x;
    if (idx >= (NC + 1) * 64) return;
    int c = idx & 63, i = idx >> 6;
    float v = bf2f(rb[idx]) * s1[c] + s1[64 + c] + bf2f(rc[idx]) * s2[c] + s2[64 + c];
    up[idx] = (i < NC) ? f2bf(v) : (u16)0;
}

extern "C" void kernel_launch(void* const* d_in, const int* in_sizes, int n_in,
                              void* d_out, int out_size, void* d_ws, size_t ws_size,
                              hipStream_t stream) {
    const float* feats_x    = (const float*)d_in[0];
    const float* feats_skip = (const float*)d_in[1];
    const float* W_trans    = (const float*)d_in[2];
    const float* W1         = (const float*)d_in[3];
    const float* W2         = (const float*)d_in[4];
    const float* W_up       = (const float*)d_in[5];
    const float* g0 = (const float*)d_in[6],  *b0 = (const float*)d_in[7];
    const float* g1 = (const float*)d_in[8],  *b1 = (const float*)d_in[9];
    const float* g2 = (const float*)d_in[10], *b2 = (const float*)d_in[11];
    const int* pairs33 = (const int*)d_in[12];
    const int* pairs13 = (const int*)d_in[13];
    const int* pairs31 = (const int*)d_in[14];
    const int* pairs_up = (const int*)d_in[15];
    float* outp = (float*)d_out;   // reference output dtype: float32

    char* ws = (char*)d_ws;
    size_t off = 0;
    auto alloc = [&](size_t bytes) {
        char* p = ws + off;
        off += (bytes + 255) & ~(size_t)255;
        return p;
    };
    u16* xp    = (u16*)alloc(30720256);   // [NC+1][128] bf16; later overlaid by inv_up
    int* inv33 = (int*)alloc(12960000);   // [27][NC]; (+inv13) later overlaid by upE
    int* inv13 = (int*)alloc(4320000);    // [9][NC]  (contiguous with inv33)
    int* inv31 = (int*)alloc(4320000);    // [9][NC]  (contiguous)
    u16* rawA  = (u16*)alloc(15360000);   // [NC][64] bf16; later rawB
    u16* rawC  = (u16*)alloc(15360000);   // [NC][64]
    u16* upA   = (u16*)alloc(15360128);   // [NC+1][64]
    u16* WtA   = (u16*)alloc(27 * 128 * 64 * 2);
    u16* Wt1   = (u16*)alloc(9 * 64 * 64 * 2);
    u16* Wt2   = (u16*)alloc(9 * 64 * 64 * 2);
    u16* WtU   = (u16*)alloc(27 * 64 * 64 * 2);
    float* stats = (float*)alloc(6 * 128 * 4);
    int* inv_up = (int*)xp;               // [27][NF] = 25.92MB — xp dead after convA
    u16* rawB = rawA;                     // rawA dead after apply0
    u16* upE  = (u16*)inv33;              // inv33+inv13 dead after convB/C
    float *sums0 = stats,        *sums1 = stats + 128, *sums2 = stats + 256;
    float *scsh0 = stats + 384,  *scsh1 = stats + 512, *scsh2 = stats + 640;

    const int B = 256;
    hipMemsetAsync(stats, 0, 6 * 128 * 4, stream);

    transpose_w_k<<<(27 * 128 * 64 + 255) / 256, B, 0, stream>>>(W_trans, WtA, 27, 128);
    transpose_w_k<<<(9 * 64 * 64 + 255) / 256, B, 0, stream>>>(W1, Wt1, 9, 64);
    transpose_w_k<<<(9 * 64 * 64 + 255) / 256, B, 0, stream>>>(W2, Wt2, 9, 64);
    transpose_w_k<<<(27 * 64 * 64 + 255) / 256, B, 0, stream>>>(W_up, WtU, 27, 64);

    add_pad_k<<<((NC + 1) * 32 + 255) / 256, B, 0, stream>>>(feats_x, feats_skip, xp);

    // inv33/inv13/inv31 are contiguous: one fill over 45*NC ints
    fill_k<<<(45 * NC + 255) / 256, B, 0, stream>>>(inv33, 45 * NC, NC);
    scatter_k<<<(27 * NC + 255) / 256, B, 0, stream>>>(pairs33, inv33, 27 * NC, NC);
    scatter_k<<<(9 * NC + 255) / 256, B, 0, stream>>>(pairs13, inv13, 9 * NC, NC);
    scatter_k<<<(9 * NC + 255) / 256, B, 0, stream>>>(pairs31, inv31, 9 * NC, NC);

    // conv_trans (27 taps, Cin=128) + leakyReLU. 625 blocks x 192 rows = 120000.
    spconv_k<128, 27, 3, true, false, 2><<<625, B, 0, stream>>>(
        xp, inv33, WtA, rawA, inv33, WtA, rawA, 625, NC, NC);
    stats2_k<<<120, B, 0, stream>>>(rawA, rawA, sums0, sums0, 120);
    finalize_k<<<1, 64, 0, stream>>>(sums0, g0, b0, scsh0);
    apply0_k<<<((NC + 1) * 64 + 255) / 256, B, 0, stream>>>(rawA, scsh0, upA);

    // xp dead — build upsample inverse map in its region
    fill_k<<<(27 * NF + 255) / 256, B, 0, stream>>>(inv_up, 27 * NF, NC);
    scatter_k<<<(27 * NC + 255) / 256, B, 0, stream>>>(pairs_up, inv_up, 27 * NC, NF);

    // conv1x3 + conv3x1 fused via grid concat: 625 + 625 blocks
    spconv_k<64, 9, 3, false, false, 3><<<1250, B, 0, stream>>>(
        upA, inv13, Wt1, rawB, inv31, Wt2, rawC, 625, NC, NC);
    stats2_k<<<240, B, 0, stream>>>(rawB, rawC, sums1, sums2, 120);
    finalize_k<<<1, 64, 0, stream>>>(sums1, g1, b1, scsh1);
    finalize_k<<<1, 64, 0, stream>>>(sums2, g2, b2, scsh2);

    apply12_k<<<((NC + 1) * 64 + 255) / 256, B, 0, stream>>>(rawB, rawC, scsh1, scsh2, upE);

    // upsample inverse conv (27 taps, Cin=64, parity skip) -> d_out (float32)
    // 1250 blocks x 192 rows = 240000.
    spconv_k<64, 27, 3, false, true, 3><<<1250, B, 0, stream>>>(
        upE, inv_up, WtU, outp, inv_up, WtU, outp, 1250, NF, NF);
}